// Round 10
// baseline (147.255 us; speedup 1.0000x reference)
//
#include <hip/hip_runtime.h>
#include <hip/hip_bf16.h>

typedef __bf16 bf16;
typedef __attribute__((ext_vector_type(8))) __bf16 bf16x8;
typedef __attribute__((ext_vector_type(4))) float floatx4;

#define PP 16
#define PPW 9
#define CFEAT 432      // C*P*PW = 3*16*9
#define EDIM 768
#define KDIM 768       // C*P*P = 3*256
#define NPAT 196
#define NBATCH 128
#define MROWS (NBATCH * NPAT)  // 25088

// prep_kernel block ranges
#define NB_W 2304                 // build_w: 768*3
#define NB_CLS 384                // cls: 128*768/256
#define NB_UNF 9408               // unfold: 25088*768/8/256
#define NB_PREP (NB_W + NB_CLS + NB_UNF)

// ---------------------------------------------------------------------------
// Kernel 1 (merged prep): build W_eff; cls row; patch-unfold x -> bf16 A.
// (unchanged — proven rounds 5..9; runs at ~HBM roofline for its 115 MB)
// ---------------------------------------------------------------------------
__global__ __launch_bounds__(256) void prep_kernel(
    const float* __restrict__ x, const float* __restrict__ pw,
    const float* __restrict__ fwh, const float* __restrict__ fww,
    const float* __restrict__ cls, const float* __restrict__ pos,
    bf16* __restrict__ Wb, bf16* __restrict__ A, float* __restrict__ out) {
  const int blk = blockIdx.x;
  const int t = threadIdx.x;

  if (blk >= NB_W + NB_CLS) {  // ---- unfold (bulk path) ----
    const int i = (blk - NB_W - NB_CLS) * 256 + t;  // < 2408448
    const int w8 = i % 28;
    const int tmp = i / 28;
    const int h = tmp % 224;
    const int tmp2 = tmp / 224;
    const int c = tmp2 % 3;
    const int b = tmp2 / 3;
    const float4 f0 = *reinterpret_cast<const float4*>(x + (size_t)i * 8);
    const float4 f1 = *reinterpret_cast<const float4*>(x + (size_t)i * 8 + 4);
    bf16x8 v;
    v[0] = (bf16)f0.x; v[1] = (bf16)f0.y; v[2] = (bf16)f0.z; v[3] = (bf16)f0.w;
    v[4] = (bf16)f1.x; v[5] = (bf16)f1.y; v[6] = (bf16)f1.z; v[7] = (bf16)f1.w;
    const int row = b * NPAT + (h >> 4) * 14 + (w8 >> 1);
    const int k = c * 256 + (h & 15) * 16 + (w8 & 1) * 8;
    *reinterpret_cast<bf16x8*>(A + (size_t)row * KDIM + k) = v;
  } else if (blk < NB_W) {  // ---- build W_eff ----
    __shared__ float s_pw[144];
    __shared__ float s_fh[16];
    __shared__ float s_fw[9];
    __shared__ float s_cos[16];
    const int e = blk / 3;
    const int c = blk % 3;
    if (t < 144) s_pw[t] = pw[e * CFEAT + c * 144 + t];
    if (t < 16) {
      s_fh[t] = fwh[t];
      s_cos[t] = cosf((float)t * 0.39269908169872414f);  // 2*pi/16
    }
    if (t < 9) s_fw[t] = fww[t];
    __syncthreads();
    const int h = t >> 4, w = t & 15;
    float acc = 0.f;
#pragma unroll
    for (int u = 0; u < 16; ++u) {
      const float fh = s_fh[u];
      const int uh = (u * h) & 15;
#pragma unroll
      for (int v = 0; v < 9; ++v) {
        acc += s_pw[u * 9 + v] * s_fw[v] * s_cos[(uh + v * w) & 15] * fh;
      }
    }
    Wb[e * KDIM + c * 256 + t] = (bf16)(acc * 0.0625f);
  } else {  // ---- cls row ----
    const int idx = (blk - NB_W) * 256 + t;  // < 128*768
    const int b = idx / 768;
    const int e = idx - b * 768;
    out[(size_t)b * 197 * 768 + e] = cls[e] + pos[e];
  }
}

// ---------------------------------------------------------------------------
// Kernel 2: LDS-FREE GEMM. 128x128 tile, 4 waves of 64x64, BK=32.
// Each lane loads its MFMA fragments DIRECTLY from global (b128 gathers;
// 4 lanes share each 64B line -> 16 lines/instr; 2-way wave reuse served by
// L1/L2; B is L2-resident).  Loop-invariant base pointers + compile-time
// immediate offsets (kt*64B <= 1472 fits the 13-bit signed imm) -> zero
// address VALU in the loop.  Register double-buffer with static indices,
// one-step lookahead; compiler inserts counted vmcnt waits.  ZERO barriers:
// no LDS, no inter-wave communication, no race class, no drain stalls.
// T1 XCD swizzle kept: grid 1176 = 8 x 147, panel-contiguous per XCD.
// ---------------------------------------------------------------------------
__global__ __launch_bounds__(256) void gemm_nolds_kernel(
    const bf16* __restrict__ A, const bf16* __restrict__ Wb,
    const float* __restrict__ pb, const float* __restrict__ pos,
    float* __restrict__ out) {
  const int bid = blockIdx.x;                    // 0..1175
  const int swz = (bid & 7) * 147 + (bid >> 3);  // XCD-chunked, bijective
  const int mt = swz / 6;                        // 0..195
  const int nt = swz - mt * 6;                   // 0..5
  const int t = threadIdx.x;
  const int l = t & 63;
  const int wv = t >> 6;
  const int wm = wv >> 1, wn = wv & 1;
  const int lr = l & 15, lq = l >> 4;

  // fragment base pointers (loop-invariant; per-kt offset is kt*32 elems)
  const bf16* baseA[4];
  const bf16* baseB[4];
#pragma unroll
  for (int mi = 0; mi < 4; ++mi)
    baseA[mi] =
        A + (size_t)(mt * 128 + wm * 64 + mi * 16 + lr) * KDIM + lq * 8;
#pragma unroll
  for (int ni = 0; ni < 4; ++ni)
    baseB[ni] =
        Wb + (size_t)(nt * 128 + wn * 64 + ni * 16 + lr) * KDIM + lq * 8;

  floatx4 acc[4][4];
#pragma unroll
  for (int i = 0; i < 4; ++i)
#pragma unroll
    for (int j = 0; j < 4; ++j) acc[i][j] = (floatx4){0.f, 0.f, 0.f, 0.f};

  bf16x8 abuf[2][4], bbuf[2][4];  // all indices compile-time (rule 20)

#define LOADF(P, kt)                                                        \
  do {                                                                      \
    _Pragma("unroll") for (int mi = 0; mi < 4; ++mi) abuf[P][mi] =          \
        *reinterpret_cast<const bf16x8*>(baseA[mi] + (kt)*32);              \
    _Pragma("unroll") for (int ni = 0; ni < 4; ++ni) bbuf[P][ni] =          \
        *reinterpret_cast<const bf16x8*>(baseB[ni] + (kt)*32);              \
  } while (0)

#define MMF(P)                                                             \
  do {                                                                     \
    _Pragma("unroll") for (int mi = 0; mi < 4; ++mi)                       \
        _Pragma("unroll") for (int ni = 0; ni < 4; ++ni) acc[mi][ni] =     \
            __builtin_amdgcn_mfma_f32_16x16x32_bf16(abuf[P][mi],           \
                                                    bbuf[P][ni],           \
                                                    acc[mi][ni], 0, 0, 0); \
  } while (0)

  LOADF(0, 0);
  LOADF(1, 1);
#pragma unroll
  for (int it = 0; it < 11; ++it) {
    MMF(0);
    LOADF(0, 2 * it + 2);  // issue next-next tile; WAR safe (in-order issue)
    MMF(1);
    LOADF(1, 2 * it + 3);
  }
  MMF(0);  // kt = 22
  MMF(1);  // kt = 23
#undef LOADF
#undef MMF

  // epilogue: out[b][1+n][e] = acc + proj_b[e] + pos_emb[1+n][e]
  float pbv[4];
#pragma unroll
  for (int ni = 0; ni < 4; ++ni)
    pbv[ni] = pb[nt * 128 + wn * 64 + ni * 16 + lr];

#pragma unroll
  for (int mi = 0; mi < 4; ++mi) {
#pragma unroll
    for (int j = 0; j < 4; ++j) {
      const unsigned m = wm * 64 + mi * 16 + lq * 4 + j;
      const unsigned Rr = mt * 128u + m;
      const unsigned b2 = Rr / 196u;
      const unsigned np2 = Rr - b2 * 196u;
      float* orow = out + ((size_t)b2 * 197 + 1 + np2) * 768;
      const float* prow = pos + (size_t)(1 + np2) * 768;
#pragma unroll
      for (int ni = 0; ni < 4; ++ni) {
        const int e = nt * 128 + wn * 64 + ni * 16 + lr;
        orow[e] = acc[mi][ni][j] + pbv[ni] + prow[e];
      }
    }
  }
}

extern "C" void kernel_launch(void* const* d_in, const int* in_sizes, int n_in,
                              void* d_out, int out_size, void* d_ws,
                              size_t ws_size, hipStream_t stream) {
  const float* x = (const float*)d_in[0];
  const float* fwh = (const float*)d_in[1];
  const float* fww = (const float*)d_in[2];
  const float* proj_w = (const float*)d_in[3];
  const float* proj_b = (const float*)d_in[4];
  const float* cls = (const float*)d_in[5];
  const float* pos = (const float*)d_in[6];
  float* out = (float*)d_out;

  const size_t needW = (size_t)EDIM * KDIM * sizeof(bf16);  // 1.18 MB
  bf16* Wb = (bf16*)d_ws;
  bf16* A = (bf16*)((char*)d_ws + needW);  // 38.5 MB

  prep_kernel<<<NB_PREP, 256, 0, stream>>>(x, proj_w, fwh, fww, cls, pos, Wb,
                                           A, out);
  gemm_nolds_kernel<<<1176, 256, 0, stream>>>(A, Wb, proj_b, pos, out);
}

// Round 11
// 113.351 us; speedup vs baseline: 1.2991x; 1.2991x over previous
//
#include <hip/hip_runtime.h>
#include <hip/hip_bf16.h>

typedef __bf16 bf16;
typedef __attribute__((ext_vector_type(8))) __bf16 bf16x8;
typedef __attribute__((ext_vector_type(4))) float floatx4;

#define PP 16
#define PPW 9
#define CFEAT 432      // C*P*PW = 3*16*9
#define EDIM 768
#define KDIM 768       // C*P*P = 3*256
#define NPAT 196
#define NBATCH 128
#define MROWS (NBATCH * NPAT)  // 25088

// prep_kernel block ranges
#define NB_W 2304                 // build_w: 768*3
#define NB_CLS 384                // cls: 128*768/256
#define NB_UNF 9408               // unfold: 25088*768/8/256
#define NB_PREP (NB_W + NB_CLS + NB_UNF)

__device__ inline void gload16(const void* g, void* l) {
  __builtin_amdgcn_global_load_lds(
      (const __attribute__((address_space(1))) void*)g,
      (__attribute__((address_space(3))) void*)l, 16, 0, 0);
}

// ---------------------------------------------------------------------------
// Kernel 1 (merged prep): build W_eff; cls row; patch-unfold x -> bf16 A.
// (unchanged — proven rounds 5..10; runs near HBM roofline for its 115 MB)
// ---------------------------------------------------------------------------
__global__ __launch_bounds__(256) void prep_kernel(
    const float* __restrict__ x, const float* __restrict__ pw,
    const float* __restrict__ fwh, const float* __restrict__ fww,
    const float* __restrict__ cls, const float* __restrict__ pos,
    bf16* __restrict__ Wb, bf16* __restrict__ A, float* __restrict__ out) {
  const int blk = blockIdx.x;
  const int t = threadIdx.x;

  if (blk >= NB_W + NB_CLS) {  // ---- unfold (bulk path) ----
    const int i = (blk - NB_W - NB_CLS) * 256 + t;  // < 2408448
    const int w8 = i % 28;
    const int tmp = i / 28;
    const int h = tmp % 224;
    const int tmp2 = tmp / 224;
    const int c = tmp2 % 3;
    const int b = tmp2 / 3;
    const float4 f0 = *reinterpret_cast<const float4*>(x + (size_t)i * 8);
    const float4 f1 = *reinterpret_cast<const float4*>(x + (size_t)i * 8 + 4);
    bf16x8 v;
    v[0] = (bf16)f0.x; v[1] = (bf16)f0.y; v[2] = (bf16)f0.z; v[3] = (bf16)f0.w;
    v[4] = (bf16)f1.x; v[5] = (bf16)f1.y; v[6] = (bf16)f1.z; v[7] = (bf16)f1.w;
    const int row = b * NPAT + (h >> 4) * 14 + (w8 >> 1);
    const int k = c * 256 + (h & 15) * 16 + (w8 & 1) * 8;
    *reinterpret_cast<bf16x8*>(A + (size_t)row * KDIM + k) = v;
  } else if (blk < NB_W) {  // ---- build W_eff ----
    __shared__ float s_pw[144];
    __shared__ float s_fh[16];
    __shared__ float s_fw[9];
    __shared__ float s_cos[16];
    const int e = blk / 3;
    const int c = blk % 3;
    if (t < 144) s_pw[t] = pw[e * CFEAT + c * 144 + t];
    if (t < 16) {
      s_fh[t] = fwh[t];
      s_cos[t] = cosf((float)t * 0.39269908169872414f);  // 2*pi/16
    }
    if (t < 9) s_fw[t] = fww[t];
    __syncthreads();
    const int h = t >> 4, w = t & 15;
    float acc = 0.f;
#pragma unroll
    for (int u = 0; u < 16; ++u) {
      const float fh = s_fh[u];
      const int uh = (u * h) & 15;
#pragma unroll
      for (int v = 0; v < 9; ++v) {
        acc += s_pw[u * 9 + v] * s_fw[v] * s_cos[(uh + v * w) & 15] * fh;
      }
    }
    Wb[e * KDIM + c * 256 + t] = (bf16)(acc * 0.0625f);
  } else {  // ---- cls row ----
    const int idx = (blk - NB_W) * 256 + t;  // < 128*768
    const int b = idx / 768;
    const int e = idx - b * 768;
    out[(size_t)b * 197 * 768 + e] = cls[e] + pos[e];
  }
}

// ---------------------------------------------------------------------------
// Kernel 2: r5 GEMM with ONE change — B fragments read DIRECTLY from global
// (B-panel = 196 KB/block, L2-certain / L1-mostly-resident; common-mistake #7:
// don't LDS-stage cache-resident data).  A keeps the proven LDS path
// (global_load_lds width-16, dbuf, STAGE(next)->COMPUTE(cur)->__syncthreads).
// B next-step gathers issue before COMPUTE into a static reg double-buffer
// (full step of latency cover).  LDS 16 KB/block.  Halves LDS reads and
// staging vmem ops.  Grid 1176 = 8 x 147 XCD-chunked (proven FETCH 33 MB).
// ---------------------------------------------------------------------------
__global__ __launch_bounds__(256) void gemm_bg_kernel(
    const bf16* __restrict__ A, const bf16* __restrict__ Wb,
    const float* __restrict__ pb, const float* __restrict__ pos,
    float* __restrict__ out) {
  __shared__ __align__(16) bf16 sA[2][128 * 32];

  const int bid = blockIdx.x;                    // 0..1175
  const int swz = (bid & 7) * 147 + (bid >> 3);  // XCD-chunked, bijective
  const int mt = swz / 6;                        // 0..195
  const int nt = swz - mt * 6;                   // 0..5
  const int t = threadIdx.x;
  const int l = t & 63;
  const int wv = t >> 6;
  const int wm = wv >> 1, wn = wv & 1;
  const int lr = l & 15, lq = l >> 4;

  // A staging: thread t covers bytes [t*16, +16) of each 4KB half-tile
  const bf16* gA0 = A + (size_t)(mt * 128 + (t >> 2)) * KDIM + (t & 3) * 8;
  const bf16* gA1 = gA0 + (size_t)64 * KDIM;
  const int lbase = wv * 512;  // wave-uniform LDS base (elems); HW adds l*16B

  // B fragment pointers (per-lane, loop-invariant)
  const bf16* baseB[4];
#pragma unroll
  for (int ni = 0; ni < 4; ++ni)
    baseB[ni] =
        Wb + (size_t)(nt * 128 + wn * 64 + ni * 16 + lr) * KDIM + lq * 8;

#define STAGEA(buf, kts)                          \
  do {                                            \
    const int ko = (kts)*32;                      \
    gload16(gA0 + ko, &sA[buf][lbase]);           \
    gload16(gA1 + ko, &sA[buf][2048 + lbase]);    \
  } while (0)

#define LOADB(P, kts)                                              \
  do {                                                             \
    _Pragma("unroll") for (int ni = 0; ni < 4; ++ni) breg[P][ni] = \
        *reinterpret_cast<const bf16x8*>(baseB[ni] + (kts)*32);    \
  } while (0)

  floatx4 acc[4][4];
#pragma unroll
  for (int i = 0; i < 4; ++i)
#pragma unroll
    for (int j = 0; j < 4; ++j) acc[i][j] = (floatx4){0.f, 0.f, 0.f, 0.f};

  bf16x8 breg[2][4];  // static indices only (rule 20)

#define COMPUTE(buf, P)                                                     \
  do {                                                                      \
    bf16x8 af[4];                                                           \
    _Pragma("unroll") for (int mi = 0; mi < 4; ++mi) {                      \
      const int r = wm * 64 + mi * 16 + lr;                                 \
      af[mi] = *reinterpret_cast<const bf16x8*>(&sA[buf][r * 32 + lq * 8]); \
    }                                                                       \
    _Pragma("unroll") for (int mi = 0; mi < 4; ++mi)                        \
        _Pragma("unroll") for (int ni = 0; ni < 4; ++ni) acc[mi][ni] =      \
            __builtin_amdgcn_mfma_f32_16x16x32_bf16(af[mi], breg[P][ni],    \
                                                    acc[mi][ni], 0, 0, 0);  \
  } while (0)

  STAGEA(0, 0);
  LOADB(0, 0);
  __syncthreads();

  // 24 K-steps, unrolled x2 for static buffer parity
#pragma unroll
  for (int it = 0; it < 11; ++it) {
    STAGEA(1, 2 * it + 1);
    LOADB(1, 2 * it + 1);
    COMPUTE(0, 0);
    __syncthreads();
    STAGEA(0, 2 * it + 2);
    LOADB(0, 2 * it + 2);
    COMPUTE(1, 1);
    __syncthreads();
  }
  STAGEA(1, 23);
  LOADB(1, 23);
  COMPUTE(0, 0);
  __syncthreads();
  COMPUTE(1, 1);
#undef STAGEA
#undef LOADB
#undef COMPUTE

  // epilogue: out[b][1+n][e] = acc + proj_b[e] + pos_emb[1+n][e]
  float pbv[4];
#pragma unroll
  for (int ni = 0; ni < 4; ++ni)
    pbv[ni] = pb[nt * 128 + wn * 64 + ni * 16 + lr];

#pragma unroll
  for (int mi = 0; mi < 4; ++mi) {
#pragma unroll
    for (int j = 0; j < 4; ++j) {
      const unsigned m = wm * 64 + mi * 16 + lq * 4 + j;
      const unsigned Rr = mt * 128u + m;
      const unsigned b2 = Rr / 196u;
      const unsigned np2 = Rr - b2 * 196u;
      float* orow = out + ((size_t)b2 * 197 + 1 + np2) * 768;
      const float* prow = pos + (size_t)(1 + np2) * 768;
#pragma unroll
      for (int ni = 0; ni < 4; ++ni) {
        const int e = nt * 128 + wn * 64 + ni * 16 + lr;
        orow[e] = acc[mi][ni][j] + pbv[ni] + prow[e];
      }
    }
  }
}

extern "C" void kernel_launch(void* const* d_in, const int* in_sizes, int n_in,
                              void* d_out, int out_size, void* d_ws,
                              size_t ws_size, hipStream_t stream) {
  const float* x = (const float*)d_in[0];
  const float* fwh = (const float*)d_in[1];
  const float* fww = (const float*)d_in[2];
  const float* proj_w = (const float*)d_in[3];
  const float* proj_b = (const float*)d_in[4];
  const float* cls = (const float*)d_in[5];
  const float* pos = (const float*)d_in[6];
  float* out = (float*)d_out;

  const size_t needW = (size_t)EDIM * KDIM * sizeof(bf16);  // 1.18 MB
  bf16* Wb = (bf16*)d_ws;
  bf16* A = (bf16*)((char*)d_ws + needW);  // 38.5 MB

  prep_kernel<<<NB_PREP, 256, 0, stream>>>(x, proj_w, fwh, fww, cls, pos, Wb,
                                           A, out);
  gemm_bg_kernel<<<1176, 256, 0, stream>>>(A, Wb, proj_b, pos, out);
}

// Round 12
// 85.911 us; speedup vs baseline: 1.7140x; 1.3194x over previous
//
#include <hip/hip_runtime.h>
#include <hip/hip_bf16.h>

typedef __bf16 bf16;
typedef __attribute__((ext_vector_type(8))) __bf16 bf16x8;
typedef __attribute__((ext_vector_type(4))) float floatx4;

#define PP 16
#define PPW 9
#define CFEAT 432      // C*P*PW = 3*16*9
#define EDIM 768
#define KDIM 768       // C*P*P = 3*256
#define NPAT 196
#define NBATCH 128
#define MROWS (NBATCH * NPAT)  // 25088

// prep_small block ranges
#define NB_W 2304   // build_w: 768*3
#define NB_CLS 384  // cls: 128*768/256

__device__ inline void gload16(const void* g, void* l) {
  __builtin_amdgcn_global_load_lds(
      (const __attribute__((address_space(1))) void*)g,
      (__attribute__((address_space(3))) void*)l, 16, 0, 0);
}

// ---------------------------------------------------------------------------
// Kernel 1: small prep — build W_eff (folded DFT*freq*proj) + cls row.
// (~2-3 us; the big unfold pass is gone — fused into the GEMM.)
// ---------------------------------------------------------------------------
__global__ __launch_bounds__(256) void prep_small(
    const float* __restrict__ pw, const float* __restrict__ fwh,
    const float* __restrict__ fww, const float* __restrict__ cls,
    const float* __restrict__ pos, bf16* __restrict__ Wb,
    float* __restrict__ out) {
  const int blk = blockIdx.x;
  const int t = threadIdx.x;
  if (blk < NB_W) {  // ---- build W_eff ----
    __shared__ float s_pw[144];
    __shared__ float s_fh[16];
    __shared__ float s_fw[9];
    __shared__ float s_cos[16];
    const int e = blk / 3;
    const int c = blk % 3;
    if (t < 144) s_pw[t] = pw[e * CFEAT + c * 144 + t];
    if (t < 16) {
      s_fh[t] = fwh[t];
      s_cos[t] = cosf((float)t * 0.39269908169872414f);  // 2*pi/16
    }
    if (t < 9) s_fw[t] = fww[t];
    __syncthreads();
    const int h = t >> 4, w = t & 15;
    float acc = 0.f;
#pragma unroll
    for (int u = 0; u < 16; ++u) {
      const float fh = s_fh[u];
      const int uh = (u * h) & 15;
#pragma unroll
      for (int v = 0; v < 9; ++v) {
        acc += s_pw[u * 9 + v] * s_fw[v] * s_cos[(uh + v * w) & 15] * fh;
      }
    }
    Wb[e * KDIM + c * 256 + t] = (bf16)(acc * 0.0625f);
  } else {  // ---- cls row ----
    const int idx = (blk - NB_W) * 256 + t;  // < 128*768
    const int b = idx / 768;
    const int e = idx - b * 768;
    out[(size_t)b * 197 * 768 + e] = cls[e] + pos[e];
  }
}

// ---------------------------------------------------------------------------
// Kernel 2: FUSED unfold+GEMM = r4's loop body + r5's XCD swizzle + r5's
// sync discipline.  128x128 tile, 4 waves 64x64, BK=32, dbuf LDS 32 KB.
//   A: x -> 4x global_load_dwordx4 (one 64B row-segment per thread, issued
//      BEFORE COMPUTE so L2 latency hides under MFMA) -> cvt -> 2 ds_write_b128
//      into the back buffer AFTER COMPUTE (T14 split).
//   B: global_load_lds width-16 (proven path).
//   One __syncthreads per K-step (drains vmcnt for B + lgkm for A writes).
// T1 swizzle: grid 1176 = 8 XCDs x 147; all 6 nt-blocks of an mt-panel run
// on ONE XCD -> the 393 KB fp32 x-panel is HBM-fetched once, L2-served 5x
// (this is what r4 lacked; its 233 MB FETCH was the regression cause).
// k-mapping: k = c*256 + hh*16 + ww ; row r of the A-tile, k-halves are the
// 16-float x segments at (c = kt>>3, hh0 = (2*kt)&15 (+half), pw*16 + ww).
// ---------------------------------------------------------------------------
__global__ __launch_bounds__(256) void gemm_fused_kernel(
    const float* __restrict__ x, const bf16* __restrict__ Wb,
    const float* __restrict__ pb, const float* __restrict__ pos,
    float* __restrict__ out) {
  __shared__ __align__(16) bf16 sA[2][128 * 32];
  __shared__ __align__(16) bf16 sB[2][128 * 32];

  const int bid = blockIdx.x;                    // 0..1175
  const int swz = (bid & 7) * 147 + (bid >> 3);  // XCD-chunked, bijective
  const int mt = swz / 6;                        // 0..195
  const int nt = swz - mt * 6;                   // 0..5
  const int t = threadIdx.x;
  const int l = t & 63;
  const int wv = t >> 6;
  const int wm = wv >> 1, wn = wv & 1;
  const int lr = l & 15, lq = l >> 4;

  // ---- A reg-staging: thread t -> A-tile row r = t>>1, k-half = t&1 ----
  const int r = t >> 1, half = t & 1;
  const int R = mt * 128 + r;  // global A row = b*196 + ph*14 + pw
  const int bb = R / 196, np = R - bb * 196;
  const int ph = np / 14, pwc = np - ph * 14;
  // base: x[bb][0][ph*16 + half][pwc*16]  (64B-aligned 16-float segment)
  const float* xbase =
      x + ((size_t)(bb * 3) * 224 + ph * 16 + half) * 224 + pwc * 16;

  // ---- B staging (global_load_lds) ----
  const bf16* gB0 = Wb + (size_t)(nt * 128 + (t >> 2)) * KDIM + (t & 3) * 8;
  const bf16* gB1 = gB0 + (size_t)64 * KDIM;
  const int lbase = wv * 512;  // wave-uniform LDS base (elems); HW adds l*16B

  floatx4 acc[4][4];
#pragma unroll
  for (int i = 0; i < 4; ++i)
#pragma unroll
    for (int j = 0; j < 4; ++j) acc[i][j] = (floatx4){0.f, 0.f, 0.f, 0.f};

  // x element offset for K-step kt (uniform): c*224*224 + hh0*224
#define KOFF(kt) ((((kt) >> 3) * 50176) + ((((kt)*2) & 15) * 224))

#define LOADX(kt, p0, p1, p2, p3)                               \
  do {                                                          \
    const float* src = xbase + KOFF(kt);                        \
    p0 = *reinterpret_cast<const float4*>(src);                 \
    p1 = *reinterpret_cast<const float4*>(src + 4);             \
    p2 = *reinterpret_cast<const float4*>(src + 8);             \
    p3 = *reinterpret_cast<const float4*>(src + 12);            \
  } while (0)

#define WRITEA(buf, p0, p1, p2, p3)                                \
  do {                                                             \
    bf16x8 a0, a1;                                                 \
    a0[0] = (bf16)p0.x; a0[1] = (bf16)p0.y;                        \
    a0[2] = (bf16)p0.z; a0[3] = (bf16)p0.w;                        \
    a0[4] = (bf16)p1.x; a0[5] = (bf16)p1.y;                        \
    a0[6] = (bf16)p1.z; a0[7] = (bf16)p1.w;                        \
    a1[0] = (bf16)p2.x; a1[1] = (bf16)p2.y;                        \
    a1[2] = (bf16)p2.z; a1[3] = (bf16)p2.w;                        \
    a1[4] = (bf16)p3.x; a1[5] = (bf16)p3.y;                        \
    a1[6] = (bf16)p3.z; a1[7] = (bf16)p3.w;                        \
    *reinterpret_cast<bf16x8*>(&sA[buf][r * 32 + half * 16]) = a0; \
    *reinterpret_cast<bf16x8*>(&sA[buf][r * 32 + half * 16 + 8]) = a1; \
  } while (0)

#define STAGEB(buf, kts)                             \
  do {                                               \
    const int ko = (kts)*32;                         \
    gload16(gB0 + ko, &sB[buf][lbase]);              \
    gload16(gB1 + ko, &sB[buf][2048 + lbase]);       \
  } while (0)

#define COMPUTE(buf)                                                         \
  do {                                                                       \
    bf16x8 af[4], bfr[4];                                                    \
    _Pragma("unroll") for (int mi = 0; mi < 4; ++mi) {                       \
      const int rr = wm * 64 + mi * 16 + lr;                                 \
      af[mi] = *reinterpret_cast<const bf16x8*>(&sA[buf][rr * 32 + lq * 8]); \
    }                                                                        \
    _Pragma("unroll") for (int ni = 0; ni < 4; ++ni) {                       \
      const int rr = wn * 64 + ni * 16 + lr;                                 \
      bfr[ni] = *reinterpret_cast<const bf16x8*>(&sB[buf][rr * 32 + lq * 8]);\
    }                                                                        \
    _Pragma("unroll") for (int mi = 0; mi < 4; ++mi)                         \
        _Pragma("unroll") for (int ni = 0; ni < 4; ++ni) acc[mi][ni] =       \
            __builtin_amdgcn_mfma_f32_16x16x32_bf16(af[mi], bfr[ni],         \
                                                    acc[mi][ni], 0, 0, 0);   \
  } while (0)

  // prologue: stage tile 0
  {
    float4 p0, p1, p2, p3;
    LOADX(0, p0, p1, p2, p3);
    STAGEB(0, 0);
    WRITEA(0, p0, p1, p2, p3);
    __syncthreads();
  }

  int cur = 0;
  for (int kt = 0; kt < 23; ++kt) {
    float4 p0, p1, p2, p3;
    LOADX(kt + 1, p0, p1, p2, p3);  // issue early: L2 latency hides under MFMA
    STAGEB(cur ^ 1, kt + 1);
    COMPUTE(cur);
    WRITEA(cur ^ 1, p0, p1, p2, p3);  // cvt+write late (T14 split)
    __syncthreads();                  // drains vmcnt (B) + lgkm (A writes)
    cur ^= 1;
  }
  COMPUTE(cur);
#undef KOFF
#undef LOADX
#undef WRITEA
#undef STAGEB
#undef COMPUTE

  // epilogue: out[b][1+n][e] = acc + proj_b[e] + pos_emb[1+n][e]
  float pbv[4];
#pragma unroll
  for (int ni = 0; ni < 4; ++ni)
    pbv[ni] = pb[nt * 128 + wn * 64 + ni * 16 + lr];

#pragma unroll
  for (int mi = 0; mi < 4; ++mi) {
#pragma unroll
    for (int j = 0; j < 4; ++j) {
      const unsigned m = wm * 64 + mi * 16 + lq * 4 + j;
      const unsigned Rr = mt * 128u + m;
      const unsigned b2 = Rr / 196u;
      const unsigned np2 = Rr - b2 * 196u;
      float* orow = out + ((size_t)b2 * 197 + 1 + np2) * 768;
      const float* prow = pos + (size_t)(1 + np2) * 768;
#pragma unroll
      for (int ni = 0; ni < 4; ++ni) {
        const int e = nt * 128 + wn * 64 + ni * 16 + lr;
        orow[e] = acc[mi][ni][j] + pbv[ni] + prow[e];
      }
    }
  }
}

extern "C" void kernel_launch(void* const* d_in, const int* in_sizes, int n_in,
                              void* d_out, int out_size, void* d_ws,
                              size_t ws_size, hipStream_t stream) {
  const float* x = (const float*)d_in[0];
  const float* fwh = (const float*)d_in[1];
  const float* fww = (const float*)d_in[2];
  const float* proj_w = (const float*)d_in[3];
  const float* proj_b = (const float*)d_in[4];
  const float* cls = (const float*)d_in[5];
  const float* pos = (const float*)d_in[6];
  float* out = (float*)d_out;

  bf16* Wb = (bf16*)d_ws;  // 768*768*2 = 1.18 MB

  prep_small<<<NB_W + NB_CLS, 256, 0, stream>>>(proj_w, fwh, fww, cls, pos,
                                                Wb, out);
  gemm_fused_kernel<<<1176, 256, 0, stream>>>(x, Wb, proj_b, pos, out);
}